// Round 1
// baseline (490.519 us; speedup 1.0000x reference)
//
#include <hip/hip_runtime.h>
#include <hip/hip_bf16.h>
#include <math.h>
#include <stdint.h>

// R5: grid-stride persistent blocks (amortize weight staging ~65x edge / ~6x node),
//     h pre-converted to bf16 (halves gather bytes, kills cvt8 in edge loop),
//     packed bf16 atomics for agg (halves atomic HBM RMW traffic),
//     /100 folded into staged qW1/pW1 rows, qW2 dot via MFMA, 8-wave blocks,
//     per-tile __syncthreads removed (sHid is wave-private, DS in-order per wave),
//     nontemporal stores for mij/out.

#define N_NODES 50000
#define N_EDGES 800000
#define DIM 64
#define HID 64
#define T_EDGE (N_EDGES / 16)   // 50000 tiles of 16 edges
#define T_NODE (N_NODES / 16)   // 3125 tiles of 16 nodes (exact)
#define EDGE_GRID 768           // 3 blocks/CU (LDS 45.5KB) * 256 CU
#define NODE_GRID 512           // 2 blocks/CU (LDS ~72KB) * 256 CU

typedef __bf16 bf16_t;
typedef __bf16 bf16x8 __attribute__((ext_vector_type(8)));
typedef float f32x4 __attribute__((ext_vector_type(4)));

__device__ __forceinline__ float silu_f(float x) {
    return x / (1.f + __expf(-x));
}

__device__ __forceinline__ f32x4 mfma16(bf16x8 a, bf16x8 b, f32x4 c) {
    return __builtin_amdgcn_mfma_f32_16x16x32_bf16(a, b, c, 0, 0, 0);
}

// load 8 consecutive fp32 (32B-aligned) and convert to a bf16 A-fragment
__device__ __forceinline__ bf16x8 cvt8(const float* __restrict__ p) {
    f32x4 u0 = *(const f32x4*)p;
    f32x4 u1 = *(const f32x4*)(p + 4);
    bf16x8 r;
    r[0] = (bf16_t)u0[0]; r[1] = (bf16_t)u0[1]; r[2] = (bf16_t)u0[2]; r[3] = (bf16_t)u0[3];
    r[4] = (bf16_t)u1[0]; r[5] = (bf16_t)u1[1]; r[6] = (bf16_t)u1[2]; r[7] = (bf16_t)u1[3];
    return r;
}

// packed bf16 atomic add (memory-side RMW, half the bytes of 2x fp32 atomics)
__device__ __forceinline__ void atomic_pk_bf16(bf16_t* p, float lo, float hi) {
    union { bf16_t h2[2]; uint32_t u; } pk;
    pk.h2[0] = (bf16_t)lo; pk.h2[1] = (bf16_t)hi;
    asm volatile("global_atomic_pk_add_bf16 %0, %1, off"
                 :: "v"((uint64_t)(uintptr_t)p), "v"(pk.u) : "memory");
}

// ---------------------------------------------------------------------------
// Zero a buffer in 16B chunks (graph-capture-safe)
// ---------------------------------------------------------------------------
__global__ __launch_bounds__(256) void zero_kernel(float* __restrict__ p, int n4)
{
    int i = blockIdx.x * 256 + threadIdx.x;
    if (i < n4) {
        f32x4 z = {0.f, 0.f, 0.f, 0.f};
        *(f32x4*)(p + (size_t)i * 4) = z;
    }
}

// ---------------------------------------------------------------------------
// h (fp32) -> hb (bf16), written into the out-region scratch (read only by
// edge_kernel, which completes before node_kernel overwrites out).
// ---------------------------------------------------------------------------
__global__ __launch_bounds__(256) void cvt_kernel(const float* __restrict__ h,
                                                  bf16_t* __restrict__ hb, int n8)
{
    int i = blockIdx.x * 256 + threadIdx.x;
    if (i < n8) {
        *(bf16x8*)(hb + (size_t)i * 8) = cvt8(h + (size_t)i * 8);
    }
}

// ---------------------------------------------------------------------------
// Edge kernel: persistent blocks, 8 waves x one 16-edge tile per iteration.
//   mij = silu(silu([hb[row]||hb[col]] @ eW1 + eb1) @ eW2 + eb2)
//   write mij (fp32, nontemporal) + packed-bf16 atomic scatter-add into agg
// ---------------------------------------------------------------------------
__global__ __launch_bounds__(512, 6) void edge_kernel(
    const bf16_t* __restrict__ hb,
    const int* __restrict__ ei,
    const float* __restrict__ eW1, const float* __restrict__ eb1,
    const float* __restrict__ eW2, const float* __restrict__ eb2,
    float* __restrict__ mij_out,
    bf16_t* __restrict__ agg)
{
    __shared__ __align__(16) bf16_t sB1[64][136];   // eW1^T [n][k], k<128
    __shared__ __align__(16) bf16_t sB2[64][72];    // eW2^T [n][k], k<64
    __shared__ __align__(16) bf16_t sHid[8][16][72];
    __shared__ float sb1[64], sb2[64];

    const int tid = threadIdx.x;
    for (int idx = tid; idx < 128 * 64; idx += 512) {
        int k = idx >> 6, n = idx & 63;
        sB1[n][k] = (bf16_t)eW1[idx];
    }
    for (int idx = tid; idx < 64 * 64; idx += 512) {
        int k = idx >> 6, n = idx & 63;
        sB2[n][k] = (bf16_t)eW2[idx];
    }
    if (tid < 64) { sb1[tid] = eb1[tid]; sb2[tid] = eb2[tid]; }
    __syncthreads();

    const int lane = tid & 63, wave = tid >> 6;
    const int m = lane & 15, quad = lane >> 4;
    const f32x4 z = {0.f, 0.f, 0.f, 0.f};

    for (int t = blockIdx.x * 8 + wave; t < T_EDGE; t += EDGE_GRID * 8) {
        const int e0 = t * 16;
        const int e = e0 + m;
        const int nrow = ei[e];
        const int ncol = ei[N_EDGES + e];
        const bf16_t* ra = hb + (size_t)nrow * DIM;
        const bf16_t* rb = hb + (size_t)ncol * DIM;

        f32x4 acc[4] = {z, z, z, z};
        #pragma unroll
        for (int ks = 0; ks < 4; ++ks) {
            const int k0 = ks * 32 + quad * 8;
            const bf16_t* src = (k0 < 64) ? (ra + k0) : (rb + (k0 - 64));
            bf16x8 a = *(const bf16x8*)src;
            #pragma unroll
            for (int nt = 0; nt < 4; ++nt) {
                bf16x8 b = *(const bf16x8*)&sB1[nt * 16 + m][k0];
                acc[nt] = mfma16(a, b, acc[nt]);
            }
        }

        #pragma unroll
        for (int nt = 0; nt < 4; ++nt) {
            #pragma unroll
            for (int rr = 0; rr < 4; ++rr) {
                int row = quad * 4 + rr;
                int col = nt * 16 + m;
                sHid[wave][row][col] = (bf16_t)silu_f(acc[nt][rr] + sb1[col]);
            }
        }
        // sHid[wave] is wave-private; DS ops are in-order per wave -> no barrier

        f32x4 acc2[4] = {z, z, z, z};
        #pragma unroll
        for (int ks = 0; ks < 2; ++ks) {
            const int k0 = ks * 32 + quad * 8;
            bf16x8 a = *(const bf16x8*)&sHid[wave][m][k0];
            #pragma unroll
            for (int nt = 0; nt < 4; ++nt) {
                bf16x8 b = *(const bf16x8*)&sB2[nt * 16 + m][k0];
                acc2[nt] = mfma16(a, b, acc2[nt]);
            }
        }

        int dstrow[4];
        #pragma unroll
        for (int rr = 0; rr < 4; ++rr) dstrow[rr] = __shfl(nrow, quad * 4 + rr);

        #pragma unroll
        for (int nt = 0; nt < 4; ++nt) {
            #pragma unroll
            for (int rr = 0; rr < 4; ++rr) {
                int row = quad * 4 + rr;
                int col = nt * 16 + m;
                float v = silu_f(acc2[nt][rr] + sb2[col]);
                __builtin_nontemporal_store(v, &mij_out[(size_t)(e0 + row) * HID + col]);
                float vh = __shfl_xor(v, 1);     // partner column's value
                if ((lane & 1) == 0) {           // even lane owns cols (col, col+1)
                    atomic_pk_bf16(agg + (size_t)dstrow[rr] * HID + col, v, vh);
                }
            }
        }
    }
}

// ---------------------------------------------------------------------------
// Node kernel: persistent blocks, 8 waves x one 16-node tile per iteration.
//   a  = [h, agg] (agg raw bf16; /100 folded into staged qW1/pW1 rows)
//   t  = silu(a @ qW1 + qb1); q_in = t @ qW2 + qb2   (MFMA, B padded to 16)
//   q_out = 3-qubit statevector circuit (fp32, 1 lane per node)
//   out = h + silu([a, q_out] @ pW1 + pb1) @ pW2 + pb2
// ---------------------------------------------------------------------------
__global__ __launch_bounds__(512, 4) void node_kernel(
    const float* __restrict__ h, const bf16_t* __restrict__ aggb,
    const float* __restrict__ qW1, const float* __restrict__ qb1,
    const float* __restrict__ qW2, const float* __restrict__ qb2,
    const float* __restrict__ pW1, const float* __restrict__ pb1,
    const float* __restrict__ pW2, const float* __restrict__ pb2,
    const float* __restrict__ al_p, const float* __restrict__ be_p,
    const float* __restrict__ ga_p, const float* __restrict__ de_p,
    const float* __restrict__ lam_p,
    float* __restrict__ out)
{
    __shared__ __align__(16) bf16_t sQ1[64][136];   // qW1^T [n][k], rows 64..127 pre-scaled *0.01
    __shared__ __align__(16) bf16_t sP1[64][168];   // pW1^T, rows 64..127 *0.01, k>=131 zero
    __shared__ __align__(16) bf16_t sP2[64][72];    // pW2^T
    __shared__ __align__(16) bf16_t sQ2b[16][72];   // qW2^T padded to 16 cols
    __shared__ __align__(16) bf16_t sHid[8][16][72];
    __shared__ float sQio[8][16][4];                // qin then qout, per wave
    __shared__ float sqb1[64], spb1[64], spb2[64], sqb2[4];

    const int tid = threadIdx.x;
    for (int idx = tid; idx < 128 * 64; idx += 512) {
        int k = idx >> 6, n = idx & 63;
        float w = qW1[idx];
        sQ1[n][k] = (bf16_t)(k < 64 ? w : w * 0.01f);
    }
    for (int idx = tid; idx < 131 * 64; idx += 512) {
        int k = idx >> 6, n = idx & 63;
        float w = pW1[idx];
        sP1[n][k] = (bf16_t)((k >= 64 && k < 128) ? w * 0.01f : w);
    }
    for (int idx = tid; idx < 37 * 64; idx += 512) {
        int k = 131 + (idx >> 6), n = idx & 63;
        sP1[n][k] = (bf16_t)0.f;
    }
    for (int idx = tid; idx < 64 * 64; idx += 512) {
        int k = idx >> 6, n = idx & 63;
        sP2[n][k] = (bf16_t)pW2[idx];
    }
    for (int idx = tid; idx < 16 * 72; idx += 512) {
        int c = idx / 72, k = idx - c * 72;
        sQ2b[c][k] = (bf16_t)((c < 3 && k < 64) ? qW2[k * 3 + c] : 0.f);
    }
    if (tid < 64) { sqb1[tid] = qb1[tid]; spb1[tid] = pb1[tid]; spb2[tid] = pb2[tid]; }
    if (tid < 3) sqb2[tid] = qb2[tid];
    __syncthreads();

    const int lane = tid & 63, wave = tid >> 6;
    const int m = lane & 15, quad = lane >> 4;
    const float al = al_p[0], be = be_p[0];
    const float ga = ga_p[0], de = de_p[0];
    const float phi01 = ga * (lam_p[1] + lam_p[3]) * 0.5f;
    const float phi02 = ga * (lam_p[2] + lam_p[6]) * 0.5f;
    const float phi12 = ga * (lam_p[5] + lam_p[7]) * 0.5f;
    const float cbg = cosf(0.5f * be), sbg = sinf(0.5f * be);
    const f32x4 z = {0.f, 0.f, 0.f, 0.f};

    for (int t = blockIdx.x * 8 + wave; t < T_NODE; t += NODE_GRID * 8) {
        const int n0 = t * 16;
        const float* hrow = h + (size_t)(n0 + m) * DIM;
        const bf16_t* grow = aggb + (size_t)(n0 + m) * HID;

        // ---- t = silu([h, agg*0.01] @ qW1 + qb1)   (scale folded into sQ1)
        f32x4 acc[4] = {z, z, z, z};
        #pragma unroll
        for (int ks = 0; ks < 4; ++ks) {
            const int k0 = ks * 32 + quad * 8;
            bf16x8 a = (k0 < 64) ? cvt8(hrow + k0)
                                 : *(const bf16x8*)(grow + (k0 - 64));
            #pragma unroll
            for (int nt = 0; nt < 4; ++nt) {
                bf16x8 b = *(const bf16x8*)&sQ1[nt * 16 + m][k0];
                acc[nt] = mfma16(a, b, acc[nt]);
            }
        }
        #pragma unroll
        for (int nt = 0; nt < 4; ++nt) {
            #pragma unroll
            for (int rr = 0; rr < 4; ++rr) {
                int row = quad * 4 + rr, col = nt * 16 + m;
                sHid[wave][row][col] = (bf16_t)silu_f(acc[nt][rr] + sqb1[col]);
            }
        }

        // ---- q_in = t @ qW2 + qb2 via MFMA (cols 3..15 are zero-padded)
        f32x4 aq = z;
        #pragma unroll
        for (int ks = 0; ks < 2; ++ks) {
            const int k0 = ks * 32 + quad * 8;
            bf16x8 a = *(const bf16x8*)&sHid[wave][m][k0];
            bf16x8 b = *(const bf16x8*)&sQ2b[m][k0];
            aq = mfma16(a, b, aq);
        }
        if (m < 3) {
            #pragma unroll
            for (int rr = 0; rr < 4; ++rr)
                sQio[wave][quad * 4 + rr][m] = aq[rr] + sqb2[m];
        }

        // ---- quantum circuit, one lane per node (reads/writes sQio in-wave)
        if (lane < 16) {
            float qin[3];
            qin[0] = sQio[wave][lane][0];
            qin[1] = sQio[wave][lane][1];
            qin[2] = sQio[wave][lane][2];
            float re[8], im[8];
            float cc[3], ssn[3];
            #pragma unroll
            for (int q = 0; q < 3; ++q) {
                float th = 0.5f * qin[q] * al;
                cc[q] = cosf(th); ssn[q] = sinf(th);
            }
            #pragma unroll
            for (int i = 0; i < 8; ++i) {   // RY data-encoding layer on |000>
                float v0 = (i & 4) ? ssn[0] : cc[0];
                float v1 = (i & 2) ? ssn[1] : cc[1];
                float v2 = (i & 1) ? ssn[2] : cc[2];
                re[i] = v0 * v1 * v2; im[i] = 0.f;
            }
            #pragma unroll
            for (int i = 0; i < 8; ++i) {   // IsingZZ coupling (diagonal)
                float z0 = (i & 4) ? -1.f : 1.f;
                float z1 = (i & 2) ? -1.f : 1.f;
                float z2 = (i & 1) ? -1.f : 1.f;
                float th = -0.5f * (phi01 * z0 * z1 + phi02 * z0 * z2 + phi12 * z1 * z2);
                float ct = cosf(th), st = sinf(th);
                float r = re[i], iM = im[i];
                re[i] = r * ct - iM * st;
                im[i] = r * st + iM * ct;
            }
            auto rx = [&](int q) {
                int msk = 4 >> q;
                #pragma unroll
                for (int i = 0; i < 8; ++i) {
                    if (i & msk) continue;
                    int j = i | msk;
                    float r0 = re[i], i0 = im[i], r1 = re[j], i1 = im[j];
                    re[i] = cbg * r0 + sbg * i1;
                    im[i] = cbg * i0 - sbg * r1;
                    re[j] = sbg * i0 + cbg * r1;
                    im[j] = -sbg * r0 + cbg * i1;
                }
            };
            auto hgate = [&](int q) {
                const float inv = 0.70710678f;
                int msk = 4 >> q;
                #pragma unroll
                for (int i = 0; i < 8; ++i) {
                    if (i & msk) continue;
                    int j = i | msk;
                    float r0 = re[i], i0 = im[i], r1 = re[j], i1 = im[j];
                    re[i] = (r0 + r1) * inv; im[i] = (i0 + i1) * inv;
                    re[j] = (r0 - r1) * inv; im[j] = (i0 - i1) * inv;
                }
            };
            auto rzg = [&](int q, float th) {
                int msk = 4 >> q;
                float c = cosf(0.5f * th), s = sinf(0.5f * th);
                #pragma unroll
                for (int i = 0; i < 8; ++i) {
                    float sg = (i & msk) ? s : -s;
                    float r = re[i], iM = im[i];
                    re[i] = r * c - iM * sg;
                    im[i] = r * sg + iM * c;
                }
            };
            rx(0); rx(1); rx(2);
            #pragma unroll
            for (int q = 0; q < 3; ++q) {
                float x = qin[q];
                rzg(q, de * (1.f - 0.5f * x * x));
                hgate(q);
                rzg(q, de * x * x);
                hgate(q);
            }
            rx(0); rx(1); rx(2);
            float e0v = 0.f, e1v = 0.f, e2v = 0.f;
            #pragma unroll
            for (int i = 0; i < 8; ++i) {
                float p = re[i] * re[i] + im[i] * im[i];
                e0v += (i & 4) ? -p : p;
                e1v += (i & 2) ? -p : p;
                e2v += (i & 1) ? -p : p;
            }
            sQio[wave][lane][0] = e0v;
            sQio[wave][lane][1] = e1v;
            sQio[wave][lane][2] = e2v;
        }

        // ---- u = silu([h, agg*0.01, q_out] @ pW1 + pb1)   (K padded 131 -> 160)
        f32x4 acc2[4] = {z, z, z, z};
        #pragma unroll
        for (int ks = 0; ks < 5; ++ks) {
            const int k0 = ks * 32 + quad * 8;
            bf16x8 a;
            if (k0 < 64) {
                a = cvt8(hrow + k0);
            } else if (k0 < 128) {
                a = *(const bf16x8*)(grow + (k0 - 64));
            } else {
                #pragma unroll
                for (int j = 0; j < 8; ++j) a[j] = (bf16_t)0.f;
                if (k0 == 128) {
                    a[0] = (bf16_t)sQio[wave][m][0];
                    a[1] = (bf16_t)sQio[wave][m][1];
                    a[2] = (bf16_t)sQio[wave][m][2];
                }
            }
            #pragma unroll
            for (int nt = 0; nt < 4; ++nt) {
                bf16x8 b = *(const bf16x8*)&sP1[nt * 16 + m][k0];
                acc2[nt] = mfma16(a, b, acc2[nt]);
            }
        }
        #pragma unroll
        for (int nt = 0; nt < 4; ++nt) {
            #pragma unroll
            for (int rr = 0; rr < 4; ++rr) {
                int row = quad * 4 + rr, col = nt * 16 + m;
                sHid[wave][row][col] = (bf16_t)silu_f(acc2[nt][rr] + spb1[col]);
            }
        }

        // ---- out = h + u @ pW2 + pb2
        f32x4 acc3[4] = {z, z, z, z};
        #pragma unroll
        for (int ks = 0; ks < 2; ++ks) {
            const int k0 = ks * 32 + quad * 8;
            bf16x8 a = *(const bf16x8*)&sHid[wave][m][k0];
            #pragma unroll
            for (int nt = 0; nt < 4; ++nt) {
                bf16x8 b = *(const bf16x8*)&sP2[nt * 16 + m][k0];
                acc3[nt] = mfma16(a, b, acc3[nt]);
            }
        }
        #pragma unroll
        for (int nt = 0; nt < 4; ++nt) {
            #pragma unroll
            for (int rr = 0; rr < 4; ++rr) {
                int row = quad * 4 + rr, col = nt * 16 + m;
                int node = n0 + row;
                float v = acc3[nt][rr] + spb2[col] + h[(size_t)node * DIM + col];
                __builtin_nontemporal_store(v, &out[(size_t)node * DIM + col]);
            }
        }
    }
}

extern "C" void kernel_launch(void* const* d_in, const int* in_sizes, int n_in,
                              void* d_out, int out_size, void* d_ws, size_t ws_size,
                              hipStream_t stream)
{
    const float* h   = (const float*)d_in[0];
    const int* ei    = (const int*)d_in[1];
    const float* eW1 = (const float*)d_in[2];
    const float* eb1 = (const float*)d_in[3];
    const float* eW2 = (const float*)d_in[4];
    const float* eb2 = (const float*)d_in[5];
    const float* qW1 = (const float*)d_in[6];
    const float* qb1 = (const float*)d_in[7];
    const float* qW2 = (const float*)d_in[8];
    const float* qb2 = (const float*)d_in[9];
    const float* pW1 = (const float*)d_in[10];
    const float* pb1 = (const float*)d_in[11];
    const float* pW2 = (const float*)d_in[12];
    const float* pb2 = (const float*)d_in[13];
    const float* al  = (const float*)d_in[14];
    const float* be  = (const float*)d_in[15];
    const float* ga  = (const float*)d_in[16];
    const float* de  = (const float*)d_in[17];
    const float* lam = (const float*)d_in[18];

    float* out = (float*)d_out;
    float* mij = out + (size_t)N_NODES * DIM;
    bf16_t* hb = (bf16_t*)d_out;          // scratch: first 6.4MB of out region,
                                          // consumed by edge_kernel, then out
                                          // is fully overwritten by node_kernel
    bf16_t* aggb = (bf16_t*)d_ws;         // bf16 aggregation buffer (6.4MB)

    const int nz4 = (N_NODES * HID * (int)sizeof(bf16_t)) / 16;  // 400000
    const int n8  = (N_NODES * DIM) / 8;                         // 400000

    zero_kernel<<<(nz4 + 255) / 256, 256, 0, stream>>>((float*)aggb, nz4);
    cvt_kernel<<<(n8 + 255) / 256, 256, 0, stream>>>(h, hb, n8);
    edge_kernel<<<EDGE_GRID, 512, 0, stream>>>(hb, ei, eW1, eb1, eW2, eb2, mij, aggb);
    node_kernel<<<NODE_GRID, 512, 0, stream>>>(h, aggb, qW1, qb1, qW2, qb2,
                                               pW1, pb1, pW2, pb2,
                                               al, be, ga, de, lam, out);
}